// Round 10
// baseline (336.142 us; speedup 1.0000x reference)
//
#include <hip/hip_runtime.h>
#include <stdint.h>

#define NX 768
#define SEQ 2048
#define NHEAD 12
#define MROWS 8192          // BATCH*SEQ
#define LN_EPS 1e-5f
#define MASK_NEG -1000000000.0f

typedef __bf16 bf16x8 __attribute__((ext_vector_type(8)));
typedef float f32x4 __attribute__((ext_vector_type(4)));

#define AS3(p)  ((__attribute__((address_space(3))) void*)(p))
#define AS1C(p) ((const __attribute__((address_space(1))) void*)(p))

__device__ __forceinline__ unsigned short f2bf(float f) {
  union { float f; unsigned int u; } v; v.f = f;
  unsigned int r = v.u + 0x7fffu + ((v.u >> 16) & 1u);
  return (unsigned short)(r >> 16);
}
__device__ __forceinline__ float bf2f(unsigned short u) {
  union { unsigned int u; float f; } v; v.u = ((unsigned int)u) << 16;
  return v.f;
}

// ---------------- fp32 -> bf16 convert (vectorized) ----------------
__global__ void convert_f32_bf16(const float* __restrict__ in,
                                 unsigned short* __restrict__ out, int n4) {
  int i = blockIdx.x * blockDim.x + threadIdx.x;
  if (i >= n4) return;
  float4 v = ((const float4*)in)[i];
  ushort4 o;
  o.x = f2bf(v.x); o.y = f2bf(v.y); o.z = f2bf(v.z); o.w = f2bf(v.w);
  ((ushort4*)out)[i] = o;
}

// ---------------- W[K][N] fp32 -> Wt[N][K] bf16 ----------------
__global__ void transpose_w(const float* __restrict__ w,
                            unsigned short* __restrict__ wt, int K, int N) {
  __shared__ float tile[32][33];
  int n0 = blockIdx.x * 32, k0 = blockIdx.y * 32;
  int tx = threadIdx.x, ty = threadIdx.y;   // (32, 8)
#pragma unroll
  for (int j = 0; j < 4; ++j)
    tile[ty + j * 8][tx] = w[(long)(k0 + ty + j * 8) * N + n0 + tx];
  __syncthreads();
#pragma unroll
  for (int j = 0; j < 4; ++j)
    wt[(long)(n0 + ty + j * 8) * K + k0 + tx] = f2bf(tile[tx][ty + j * 8]);
}

// ---------------- V slice of qkv -> Vt[bh][d][s], vectorized ----------------
__global__ void transpose_v(const unsigned short* __restrict__ qkv,
                            unsigned short* __restrict__ vt) {
  __shared__ unsigned short tile[64][68];
  int s0 = blockIdx.x * 64;
  int bh = blockIdx.y, b = bh / NHEAD, h = bh % NHEAD;
  int tx = threadIdx.x, ty = threadIdx.y;
  const unsigned short* src = qkv + (long)b * SEQ * 2304 + 1536 + h * 64;
#pragma unroll
  for (int j = 0; j < 4; ++j) {
    int s = ty + j * 16;
    ushort4 vv = *(const ushort4*)(src + (long)(s0 + s) * 2304 + tx * 4);
    *(ushort4*)(&tile[s][tx * 4]) = vv;
  }
  __syncthreads();
  unsigned short* dst = vt + (long)bh * 64 * SEQ + s0;
#pragma unroll
  for (int j = 0; j < 4; ++j) {
    int d = ty + j * 16;
    ushort4 o;
    o.x = tile[tx * 4 + 0][d]; o.y = tile[tx * 4 + 1][d];
    o.z = tile[tx * 4 + 2][d]; o.w = tile[tx * 4 + 3][d];
    *(ushort4*)(dst + (long)d * SEQ + tx * 4) = o;
  }
}

// ---------------- GEMM: C[M][N] = A[M][K] @ Bt[N][K]^T + bias ----------------
// 128 x BN tile, BK=64, single-barrier double-buffered K-loop.
// Grid (M fast, N slow): same-m0 blocks are 64 ids apart (≡0 mod 8) so each
// A-slab is XCD-pinned. Staging pointers hoisted out of the loop (attn pattern).
template <int ACT, int BN>   // ACT: 0 none, 1 relu
__global__ __launch_bounds__(256) void gemm_bt(const unsigned short* __restrict__ A,
                                               const unsigned short* __restrict__ Bt,
                                               const float* __restrict__ bias,
                                               unsigned short* __restrict__ C,
                                               int Nsz, int K) {
  constexpr int ABUF = 128 * 64;
  constexpr int BBUF = BN * 64;
  constexpr int BUF = ABUF + BBUF;
  __shared__ __align__(16) unsigned short smem[2 * BUF];
  const int tid = threadIdx.x;
  const int w = tid >> 6, lane = tid & 63;
  const int l15 = lane & 15, quad = lane >> 4;
  constexpr int MT = (BN == 128) ? 4 : 2;
  const int wrow0 = (BN == 128) ? (w >> 1) * 64 : w * 32;
  const int wcol0 = (BN == 128) ? (w & 1) * 64 : 0;
  const long m0 = (long)blockIdx.x * 128;   // fast axis = M
  const long n0 = (long)blockIdx.y * BN;

  const int srow = tid >> 3;
  const int sg = tid & 7;

  // hoisted staging pointers (incremented by 64 elems per K-tile)
  const unsigned short* ap[4];
#pragma unroll
  for (int p = 0; p < 4; ++p) {
    int row = p * 32 + srow;
    ap[p] = A + (m0 + row) * (long)K + (sg ^ (row & 7)) * 8;
  }
  const unsigned short* bp[BN / 32];
#pragma unroll
  for (int p = 0; p < BN / 32; ++p) {
    int row = p * 32 + srow;
    bp[p] = Bt + (n0 + row) * (long)K + (sg ^ (row & 7)) * 8;
  }

  auto stage = [&](int kb) {
    unsigned short* As = smem + (kb & 1) * BUF;
    unsigned short* Bs = As + ABUF;
#pragma unroll
    for (int p = 0; p < 4; ++p) {
      __builtin_amdgcn_global_load_lds(AS1C(ap[p]), AS3(As + p * 2048 + w * 512), 16, 0, 0);
      ap[p] += 64;
    }
#pragma unroll
    for (int p = 0; p < BN / 32; ++p) {
      __builtin_amdgcn_global_load_lds(AS1C(bp[p]), AS3(Bs + p * 2048 + w * 512), 16, 0, 0);
      bp[p] += 64;
    }
  };

  f32x4 acc[MT][4] = {};
  const int nkb = K / 64;

  stage(0);
  for (int kb = 0; kb < nkb; ++kb) {
    __syncthreads();              // publish buf[kb&1]; drains loads issued last iter
    if (kb + 1 < nkb) stage(kb + 1);
    const unsigned short* As = smem + (kb & 1) * BUF;
    const unsigned short* Bs = As + ABUF;
#pragma unroll
    for (int s2 = 0; s2 < 2; ++s2) {
      const int phys = ((s2 * 4 + quad) ^ (l15 & 7)) * 8;
      bf16x8 af[MT], bfr[4];
#pragma unroll
      for (int mt = 0; mt < MT; ++mt)
        af[mt] = *(const bf16x8*)(As + (wrow0 + mt * 16 + l15) * 64 + phys);
#pragma unroll
      for (int nt = 0; nt < 4; ++nt)
        bfr[nt] = *(const bf16x8*)(Bs + (wcol0 + nt * 16 + l15) * 64 + phys);
#pragma unroll
      for (int mt = 0; mt < MT; ++mt)
#pragma unroll
        for (int nt = 0; nt < 4; ++nt)
          acc[mt][nt] = __builtin_amdgcn_mfma_f32_16x16x32_bf16(af[mt], bfr[nt], acc[mt][nt], 0, 0, 0);
    }
  }
  __syncthreads();   // all waves done with LDS before epilogue reuses it

  // ---- epilogue: bias/act -> per-wave LDS slab -> b128 coalesced stores ----
  unsigned short* Ew = smem + w * (16 * 72);
  const long gmB = m0 + wrow0;
  const long gnB = n0 + wcol0;
  float bv[4];
#pragma unroll
  for (int nt = 0; nt < 4; ++nt) bv[nt] = bias[gnB + nt * 16 + l15];
  const int prow = lane >> 3, pcol = (lane & 7) * 8;
#pragma unroll
  for (int mt = 0; mt < MT; ++mt) {
#pragma unroll
    for (int nt = 0; nt < 4; ++nt)
#pragma unroll
      for (int r = 0; r < 4; ++r) {
        float v = acc[mt][nt][r] + bv[nt];
        if (ACT == 1) v = fmaxf(v, 0.f);
        Ew[(quad * 4 + r) * 72 + nt * 16 + l15] = f2bf(v);
      }
#pragma unroll
    for (int ps = 0; ps < 2; ++ps) {
      int row = ps * 8 + prow;
      int4 t = *(const int4*)(Ew + row * 72 + pcol);
      *(int4*)(C + (gmB + mt * 16 + row) * (long)Nsz + gnB + pcol) = t;
    }
  }
}

// ---------------- flash attention v14: v11 + balanced bx remap (best: 48.0-48.7 us) ----------------
// Per-block code identical to proven v11. The j -> (bx, bh-group) remap makes
// every CU's bx-triple sum 22/23 (r=j>>5, t=j&15; bx = [t, (t+8)&15,
// t<8?15-2t:30-2t][r]; bh-group = 2r+((j>>4)&1), bijective). Measured: -1%
// vs v11 — the balance was already near mean; the remaining 1570 cy/iter is
// the latency chain (barrier + LDS round-trips), not imbalance. Local floor.
__global__ __launch_bounds__(512) void attn_v14(const unsigned short* __restrict__ qkv,
                                                const unsigned short* __restrict__ vt,
                                                unsigned short* __restrict__ out) {
  const int blk = blockIdx.x;           // 0..767
  const int bh_lo = blk & 7;
  const int j = blk >> 3;               // 0..95
  const int r = j >> 5;                 // 0..2  (CU gets one j from each r)
  const int t = j & 15;
  int bx;
  if (r == 0)      bx = t;
  else if (r == 1) bx = (t + 8) & 15;
  else             bx = (t < 8) ? (15 - 2 * t) : (30 - 2 * t);
  const int bhHi6 = 2 * r + ((j >> 4) & 1);   // 0..5
  const int bh = bhHi6 * 8 + bh_lo;     // 0..47
  const int b = bh / NHEAD, h = bh % NHEAD;
  const int tid = threadIdx.x;
  const int w = tid >> 6;               // 0..7
  const int wl = w & 3;                 // wave within group
  const int g = w >> 2;                 // 0 = group A (heavy), 1 = group B
  const int lane = tid & 63, l15 = lane & 15, quad = lane >> 4;

  const int qtA = 31 - bx;              // heavy tile
  const int qtB = bx;                   // light tile
  const int qt = g ? qtB : qtA;         // this wave-group's tile
  const int niter = qtA + 1;
  const int nact = qt + 1;              // iterations this group computes

  __shared__ __align__(16) unsigned short Ks[2][64 * 64];   // [key][d], gran ^ key&7
  __shared__ __align__(16) unsigned short Vs[2][64 * 64];   // [d][key], gran ^ d&7
  __shared__ __align__(16) unsigned short Ps[8][16 * 64];   // per-wave [q][key]

  const long rowbase = (long)b * SEQ;
  unsigned short* Pw = &Ps[w][0];
  const unsigned short* vbh = vt + (long)bh * 64 * SEQ;
  const float LOG2E = 1.4426950408889634f;

  // staging: 512 threads cover one 64x64 K tile + one 64x64 V tile (16B each)
  const int krow = tid >> 3;                         // 0..63
  const int kgo = (((tid & 7) ^ (krow & 7)) * 8);    // swizzled granule offset
  const unsigned short* kbase = qkv + rowbase * 2304L + 768 + h * 64;
  const unsigned short* kp = kbase + (long)krow * 2304 + kgo;
  const unsigned short* vp = vbh + (long)krow * SEQ + kgo;

  // ---- Q for this group's tile (folded * LOG2E) ----
  const int qrow = qt * 64 + wl * 16 + l15;
  const int qg = qrow;
  bf16x8 qf[2];
#pragma unroll
  for (int s2 = 0; s2 < 2; ++s2) {
    int4 raw = *(const int4*)(qkv + (rowbase + qrow) * 2304L + h * 64 + s2 * 32 + quad * 8);
    const unsigned short* rp = (const unsigned short*)&raw;
#pragma unroll
    for (int j2 = 0; j2 < 8; ++j2)
      qf[s2][j2] = (__bf16)(bf2f(rp[j2]) * LOG2E);
  }

  float l_sum = 0.f;
  f32x4 o_acc[4] = {};

  // prologue: stage tile 0 into buf 0 (one K + one V load per thread)
  __builtin_amdgcn_global_load_lds(AS1C(kp), AS3(&Ks[0][0] + w * 512), 16, 0, 0);
  __builtin_amdgcn_global_load_lds(AS1C(vp), AS3(&Vs[0][0] + w * 512), 16, 0, 0);
  kp += 64 * 2304;
  vp += 64;

  for (int it = 0; it < niter; ++it) {
    __syncthreads();   // publish buf[it&1]; prefetched loads had a full iter to land
    if (it + 1 < niter) {
      const int nb = (it + 1) & 1;
      __builtin_amdgcn_global_load_lds(AS1C(kp), AS3(&Ks[nb][0] + w * 512), 16, 0, 0);
      __builtin_amdgcn_global_load_lds(AS1C(vp), AS3(&Vs[nb][0] + w * 512), 16, 0, 0);
      kp += 64 * 2304;
      vp += 64;
    }
    if (it >= nact) continue;   // group B done computing; stage + barrier only
    const unsigned short* Kc = &Ks[it & 1][0];
    const unsigned short* Vc = &Vs[it & 1][0];

    // ---- S^T = K Q^T : st[nt] rows = keys nt*16+quad*4+r, col q = l15 ----
    f32x4 st[4] = {};
    __builtin_amdgcn_s_setprio(1);
#pragma unroll
    for (int nt = 0; nt < 4; ++nt) {
      int key = nt * 16 + l15;
#pragma unroll
      for (int s2 = 0; s2 < 2; ++s2) {
        int phys = (s2 * 4 + quad) ^ (key & 7);
        bf16x8 kf = *(const bf16x8*)(Kc + key * 64 + phys * 8);
        st[nt] = __builtin_amdgcn_mfma_f32_16x16x32_bf16(kf, qf[s2], st[nt], 0, 0, 0);
      }
    }
    __builtin_amdgcn_s_setprio(0);

    // ---- causal mask: only this group's diagonal tile (it == qt) ----
    if (it == qt) {
#pragma unroll
      for (int nt = 0; nt < 4; ++nt) {
        int kg = it * 64 + nt * 16 + quad * 4;
#pragma unroll
        for (int rr = 0; rr < 4; ++rr)
          if (kg + rr > qg) st[nt][rr] = MASK_NEG;
      }
    }

    // ---- fixed-max softmax: p = 2^s ; per-lane partial, tree-reduced ----
    float sn[4];
#pragma unroll
    for (int nt = 0; nt < 4; ++nt) {
      float p0 = __builtin_amdgcn_exp2f(st[nt][0]);
      float p1 = __builtin_amdgcn_exp2f(st[nt][1]);
      float p2 = __builtin_amdgcn_exp2f(st[nt][2]);
      float p3 = __builtin_amdgcn_exp2f(st[nt][3]);
      st[nt][0] = p0; st[nt][1] = p1; st[nt][2] = p2; st[nt][3] = p3;
      sn[nt] = (p0 + p1) + (p2 + p3);
    }
    l_sum += (sn[0] + sn[1]) + (sn[2] + sn[3]);   // cross-quad reduce deferred

    // ---- P: cvt_pk pack 4 keys -> b64 store (granule ^ l15&7) ----
#pragma unroll
    for (int nt = 0; nt < 4; ++nt) {
      unsigned int lo, hi;
      asm("v_cvt_pk_bf16_f32 %0, %1, %2" : "=v"(lo) : "v"(st[nt][0]), "v"(st[nt][1]));
      asm("v_cvt_pk_bf16_f32 %0, %1, %2" : "=v"(hi) : "v"(st[nt][2]), "v"(st[nt][3]));
      int g8 = (nt * 2 + (quad >> 1)) ^ (l15 & 7);
      uint2 pv; pv.x = lo; pv.y = hi;
      *(uint2*)(Pw + l15 * 64 + g8 * 8 + (quad & 1) * 4) = pv;
    }

    // ---- O += P V  (same-wave LDS dependency, no barrier) ----
    __builtin_amdgcn_s_setprio(1);
#pragma unroll
    for (int c = 0; c < 2; ++c) {
      int phys = ((c * 4 + quad) ^ (l15 & 7)) * 8;
      bf16x8 pf = *(const bf16x8*)(Pw + l15 * 64 + phys);
#pragma unroll
      for (int ntd = 0; ntd < 4; ++ntd) {
        int d = ntd * 16 + l15;
        bf16x8 vf = *(const bf16x8*)(Vc + d * 64 + phys);
        o_acc[ntd] = __builtin_amdgcn_mfma_f32_16x16x32_bf16(pf, vf, o_acc[ntd], 0, 0, 0);
      }
    }
    __builtin_amdgcn_s_setprio(0);
  }

  // ---- epilogue: complete l_sum reduce, then O row q = quad*4+r ----
  l_sum += __shfl_xor(l_sum, 16);
  l_sum += __shfl_xor(l_sum, 32);
#pragma unroll
  for (int rr = 0; rr < 4; ++rr) {
    float lq = __shfl(l_sum, quad * 4 + rr);
    float inv = 1.f / lq;
    int q = qt * 64 + wl * 16 + quad * 4 + rr;
#pragma unroll
    for (int ntd = 0; ntd < 4; ++ntd) {
      int d = ntd * 16 + l15;
      out[(rowbase + q) * (long)NX + h * 64 + d] = f2bf(o_acc[ntd][rr] * inv);
    }
  }
}

// ---------------- fused residual add + (buggy additive) layernorm ----------------
__global__ __launch_bounds__(256) void add_ln(const float* __restrict__ x_f,
                                              const unsigned short* __restrict__ x_b,
                                              const unsigned short* __restrict__ y_b,
                                              const float* __restrict__ g,
                                              const float* __restrict__ beta,
                                              float* __restrict__ out_f,
                                              unsigned short* __restrict__ out_b) {
  const int row = blockIdx.x, t = threadIdx.x;
  const long base = (long)row * NX;
  float v[3];
#pragma unroll
  for (int j = 0; j < 3; ++j) {
    int i = t + j * 256;
    float a = x_f ? x_f[base + i] : bf2f(x_b[base + i]);
    v[j] = a + bf2f(y_b[base + i]);
  }
  __shared__ float red[4];
  int wv = t >> 6, ln = t & 63;

  float ssum = v[0] + v[1] + v[2];
#pragma unroll
  for (int sh = 32; sh >= 1; sh >>= 1) ssum += __shfl_xor(ssum, sh);
  if (ln == 0) red[wv] = ssum;
  __syncthreads();
  float u = (red[0] + red[1] + red[2] + red[3]) * (1.f / NX);
  __syncthreads();

  float d0 = v[0] - u, d1 = v[1] - u, d2 = v[2] - u;
  float sq = d0 * d0 + d1 * d1 + d2 * d2;
#pragma unroll
  for (int sh = 32; sh >= 1; sh >>= 1) sq += __shfl_xor(sq, sh);
  if (ln == 0) red[wv] = sq;
  __syncthreads();
  float s = (red[0] + red[1] + red[2] + red[3]) * (1.f / NX);
  float rinv = rsqrtf(s + LN_EPS);

  float dd[3] = {d0, d1, d2};
#pragma unroll
  for (int j = 0; j < 3; ++j) {
    int i = t + j * 256;
    float o = g[i] + dd[j] * rinv + beta[i];
    if (out_f) out_f[base + i] = o;
    else out_b[base + i] = f2bf(o);
  }
}

extern "C" void kernel_launch(void* const* d_in, const int* in_sizes, int n_in,
                              void* d_out, int out_size, void* d_ws, size_t ws_size,
                              hipStream_t stream) {
  const float* x      = (const float*)d_in[0];
  const float* w_attn = (const float*)d_in[1];
  const float* b_attn = (const float*)d_in[2];
  const float* w_proj = (const float*)d_in[3];
  const float* b_proj = (const float*)d_in[4];
  const float* ln1_g  = (const float*)d_in[5];
  const float* ln1_b  = (const float*)d_in[6];
  const float* w_fc   = (const float*)d_in[7];
  const float* b_fc   = (const float*)d_in[8];
  const float* w_fc2  = (const float*)d_in[9];
  const float* b_fc2  = (const float*)d_in[10];
  const float* ln2_g  = (const float*)d_in[11];
  const float* ln2_b  = (const float*)d_in[12];
  float* out = (float*)d_out;

  char* ws = (char*)d_ws;
  size_t off = 0;
  auto alloc = [&](size_t bytes) {
    char* p = ws + off;
    off += (bytes + 255) & ~(size_t)255;
    return p;
  };
  unsigned short* xb      = (unsigned short*)alloc((size_t)MROWS * NX * 2);
  unsigned short* wt_attn = (unsigned short*)alloc((size_t)2304 * 768 * 2);
  unsigned short* wt_proj = (unsigned short*)alloc((size_t)768 * 768 * 2);
  unsigned short* wt_fc   = (unsigned short*)alloc((size_t)3072 * 768 * 2);
  unsigned short* wt_fc2  = (unsigned short*)alloc((size_t)768 * 3072 * 2);
  unsigned short* qkv     = (unsigned short*)alloc((size_t)MROWS * 3072 * 2);
  unsigned short* hbuf    = qkv;        // fc output reuses qkv (dead after attn)
  unsigned short* abuf    = (unsigned short*)alloc((size_t)MROWS * NX * 2);
  unsigned short* mbuf    = abuf;       // fc2 output reuses abuf (dead after proj)
  unsigned short* nbuf    = (unsigned short*)alloc((size_t)MROWS * NX * 2);
  unsigned short* vtb     = nbuf;       // Vt[bh][d][s] lives in nbuf (dead until add_ln1)
  unsigned short* pout    = xb;         // proj output reuses xb (dead after qkv gemm)

  convert_f32_bf16<<<(MROWS * NX / 4 + 255) / 256, 256, 0, stream>>>(x, xb, MROWS * NX / 4);
  transpose_w<<<dim3(2304 / 32, 768 / 32), dim3(32, 8), 0, stream>>>(w_attn, wt_attn, 768, 2304);
  transpose_w<<<dim3(768 / 32, 768 / 32), dim3(32, 8), 0, stream>>>(w_proj, wt_proj, 768, 768);
  transpose_w<<<dim3(3072 / 32, 768 / 32), dim3(32, 8), 0, stream>>>(w_fc, wt_fc, 768, 3072);
  transpose_w<<<dim3(768 / 32, 3072 / 32), dim3(32, 8), 0, stream>>>(w_fc2, wt_fc2, 3072, 768);

  // qkv = xb @ w_attn^T + b_attn   (BN=128: 1152 blocks @ 2/CU, proven -7us)
  gemm_bt<0, 128><<<dim3(MROWS / 128, 2304 / 128), 256, 0, stream>>>(xb, wt_attn, b_attn, qkv, 2304, 768);
  // Vt[bh][d][s]
  transpose_v<<<dim3(SEQ / 64, 48), dim3(16, 16), 0, stream>>>(qkv, vtb);
  // a = causal_attention(qkv)  (768 pair-blocks, balanced bx remap)
  attn_v14<<<768, 512, 0, stream>>>(qkv, vtb, abuf);
  // pout = a @ w_proj^T + b_proj   (BN=128: 384 blocks, 1.5/CU, both resident)
  gemm_bt<0, 128><<<dim3(MROWS / 128, 768 / 128), 256, 0, stream>>>(abuf, wt_proj, b_proj, pout, 768, 768);
  // n = ln1(x + pout)   (overwrites nbuf == vtb, Vt is dead now)
  add_ln<<<MROWS, 256, 0, stream>>>(x, nullptr, pout, ln1_g, ln1_b, nullptr, nbuf);
  // h = relu(n @ w_fc^T + b_fc)   (1536 blocks = exactly 3 rounds @ 2/CU)
  gemm_bt<1, 128><<<dim3(MROWS / 128, 3072 / 128), 256, 0, stream>>>(nbuf, wt_fc, b_fc, hbuf, 3072, 768);
  // m = h @ w_fc2^T + b_fc2   (BN=128: 384 blocks, K=3072 amortizes well)
  gemm_bt<0, 128><<<dim3(MROWS / 128, 768 / 128), 256, 0, stream>>>(hbuf, wt_fc2, b_fc2, mbuf, 768, 3072);
  // out = ln2(n + m)  (fp32 to d_out)
  add_ln<<<MROWS, 256, 0, stream>>>(nullptr, nbuf, mbuf, ln2_g, ln2_b, out, nullptr);
}

// Round 11
// 331.446 us; speedup vs baseline: 1.0142x; 1.0142x over previous
//
#include <hip/hip_runtime.h>
#include <stdint.h>

#define NX 768
#define SEQ 2048
#define NHEAD 12
#define MROWS 8192          // BATCH*SEQ
#define LN_EPS 1e-5f
#define MASK_NEG -1000000000.0f

typedef __bf16 bf16x8 __attribute__((ext_vector_type(8)));
typedef float f32x4 __attribute__((ext_vector_type(4)));

#define AS3(p)  ((__attribute__((address_space(3))) void*)(p))
#define AS1C(p) ((const __attribute__((address_space(1))) void*)(p))

__device__ __forceinline__ unsigned short f2bf(float f) {
  union { float f; unsigned int u; } v; v.f = f;
  unsigned int r = v.u + 0x7fffu + ((v.u >> 16) & 1u);
  return (unsigned short)(r >> 16);
}
__device__ __forceinline__ float bf2f(unsigned short u) {
  union { unsigned int u; float f; } v; v.u = ((unsigned int)u) << 16;
  return v.f;
}

// ---------------- fp32 -> bf16 convert (vectorized) ----------------
__global__ void convert_f32_bf16(const float* __restrict__ in,
                                 unsigned short* __restrict__ out, int n4) {
  int i = blockIdx.x * blockDim.x + threadIdx.x;
  if (i >= n4) return;
  float4 v = ((const float4*)in)[i];
  ushort4 o;
  o.x = f2bf(v.x); o.y = f2bf(v.y); o.z = f2bf(v.z); o.w = f2bf(v.w);
  ((ushort4*)out)[i] = o;
}

// ---------------- W[K][N] fp32 -> Wt[N][K] bf16 ----------------
__global__ void transpose_w(const float* __restrict__ w,
                            unsigned short* __restrict__ wt, int K, int N) {
  __shared__ float tile[32][33];
  int n0 = blockIdx.x * 32, k0 = blockIdx.y * 32;
  int tx = threadIdx.x, ty = threadIdx.y;   // (32, 8)
#pragma unroll
  for (int j = 0; j < 4; ++j)
    tile[ty + j * 8][tx] = w[(long)(k0 + ty + j * 8) * N + n0 + tx];
  __syncthreads();
#pragma unroll
  for (int j = 0; j < 4; ++j)
    wt[(long)(n0 + ty + j * 8) * K + k0 + tx] = f2bf(tile[tx][ty + j * 8]);
}

// ---------------- V slice of qkv -> Vt[bh][d][s], vectorized ----------------
__global__ void transpose_v(const unsigned short* __restrict__ qkv,
                            unsigned short* __restrict__ vt) {
  __shared__ unsigned short tile[64][68];
  int s0 = blockIdx.x * 64;
  int bh = blockIdx.y, b = bh / NHEAD, h = bh % NHEAD;
  int tx = threadIdx.x, ty = threadIdx.y;
  const unsigned short* src = qkv + (long)b * SEQ * 2304 + 1536 + h * 64;
#pragma unroll
  for (int j = 0; j < 4; ++j) {
    int s = ty + j * 16;
    ushort4 vv = *(const ushort4*)(src + (long)(s0 + s) * 2304 + tx * 4);
    *(ushort4*)(&tile[s][tx * 4]) = vv;
  }
  __syncthreads();
  unsigned short* dst = vt + (long)bh * 64 * SEQ + s0;
#pragma unroll
  for (int j = 0; j < 4; ++j) {
    int d = ty + j * 16;
    ushort4 o;
    o.x = tile[tx * 4 + 0][d]; o.y = tile[tx * 4 + 1][d];
    o.z = tile[tx * 4 + 2][d]; o.w = tile[tx * 4 + 3][d];
    *(ushort4*)(dst + (long)d * SEQ + tx * 4) = o;
  }
}

// ---------------- GEMM: C[M][N] = A[M][K] @ Bt[N][K]^T + bias ----------------
// 128 x BN tile, BK=64, single-barrier double-buffered K-loop.
// Grid (M fast, N slow): same-m0 blocks are 64 ids apart (≡0 mod 8) so each
// A-slab is XCD-pinned. Staging pointers hoisted out of the loop (attn pattern).
// Tile choice per shape (measured): BN=128 wins when blocks >= 2/CU for all
// rounds (qkv: 1152 blocks, fc: 1536). BN=64 wins for N=768 outputs (proj,
// fc2): 768 blocks = exactly 3/CU at 48KB LDS; BN=128's 384 blocks = 1.5/CU
// = 12% occupancy, fc2 regressed to 49.4us (R10 counters).
template <int ACT, int BN>   // ACT: 0 none, 1 relu
__global__ __launch_bounds__(256) void gemm_bt(const unsigned short* __restrict__ A,
                                               const unsigned short* __restrict__ Bt,
                                               const float* __restrict__ bias,
                                               unsigned short* __restrict__ C,
                                               int Nsz, int K) {
  constexpr int ABUF = 128 * 64;
  constexpr int BBUF = BN * 64;
  constexpr int BUF = ABUF + BBUF;
  __shared__ __align__(16) unsigned short smem[2 * BUF];
  const int tid = threadIdx.x;
  const int w = tid >> 6, lane = tid & 63;
  const int l15 = lane & 15, quad = lane >> 4;
  constexpr int MT = (BN == 128) ? 4 : 2;
  const int wrow0 = (BN == 128) ? (w >> 1) * 64 : w * 32;
  const int wcol0 = (BN == 128) ? (w & 1) * 64 : 0;
  const long m0 = (long)blockIdx.x * 128;   // fast axis = M
  const long n0 = (long)blockIdx.y * BN;

  const int srow = tid >> 3;
  const int sg = tid & 7;

  // hoisted staging pointers (incremented by 64 elems per K-tile)
  const unsigned short* ap[4];
#pragma unroll
  for (int p = 0; p < 4; ++p) {
    int row = p * 32 + srow;
    ap[p] = A + (m0 + row) * (long)K + (sg ^ (row & 7)) * 8;
  }
  const unsigned short* bp[BN / 32];
#pragma unroll
  for (int p = 0; p < BN / 32; ++p) {
    int row = p * 32 + srow;
    bp[p] = Bt + (n0 + row) * (long)K + (sg ^ (row & 7)) * 8;
  }

  auto stage = [&](int kb) {
    unsigned short* As = smem + (kb & 1) * BUF;
    unsigned short* Bs = As + ABUF;
#pragma unroll
    for (int p = 0; p < 4; ++p) {
      __builtin_amdgcn_global_load_lds(AS1C(ap[p]), AS3(As + p * 2048 + w * 512), 16, 0, 0);
      ap[p] += 64;
    }
#pragma unroll
    for (int p = 0; p < BN / 32; ++p) {
      __builtin_amdgcn_global_load_lds(AS1C(bp[p]), AS3(Bs + p * 2048 + w * 512), 16, 0, 0);
      bp[p] += 64;
    }
  };

  f32x4 acc[MT][4] = {};
  const int nkb = K / 64;

  stage(0);
  for (int kb = 0; kb < nkb; ++kb) {
    __syncthreads();              // publish buf[kb&1]; drains loads issued last iter
    if (kb + 1 < nkb) stage(kb + 1);
    const unsigned short* As = smem + (kb & 1) * BUF;
    const unsigned short* Bs = As + ABUF;
#pragma unroll
    for (int s2 = 0; s2 < 2; ++s2) {
      const int phys = ((s2 * 4 + quad) ^ (l15 & 7)) * 8;
      bf16x8 af[MT], bfr[4];
#pragma unroll
      for (int mt = 0; mt < MT; ++mt)
        af[mt] = *(const bf16x8*)(As + (wrow0 + mt * 16 + l15) * 64 + phys);
#pragma unroll
      for (int nt = 0; nt < 4; ++nt)
        bfr[nt] = *(const bf16x8*)(Bs + (wcol0 + nt * 16 + l15) * 64 + phys);
#pragma unroll
      for (int mt = 0; mt < MT; ++mt)
#pragma unroll
        for (int nt = 0; nt < 4; ++nt)
          acc[mt][nt] = __builtin_amdgcn_mfma_f32_16x16x32_bf16(af[mt], bfr[nt], acc[mt][nt], 0, 0, 0);
    }
  }
  __syncthreads();   // all waves done with LDS before epilogue reuses it

  // ---- epilogue: bias/act -> per-wave LDS slab -> b128 coalesced stores ----
  unsigned short* Ew = smem + w * (16 * 72);
  const long gmB = m0 + wrow0;
  const long gnB = n0 + wcol0;
  float bv[4];
#pragma unroll
  for (int nt = 0; nt < 4; ++nt) bv[nt] = bias[gnB + nt * 16 + l15];
  const int prow = lane >> 3, pcol = (lane & 7) * 8;
#pragma unroll
  for (int mt = 0; mt < MT; ++mt) {
#pragma unroll
    for (int nt = 0; nt < 4; ++nt)
#pragma unroll
      for (int r = 0; r < 4; ++r) {
        float v = acc[mt][nt][r] + bv[nt];
        if (ACT == 1) v = fmaxf(v, 0.f);
        Ew[(quad * 4 + r) * 72 + nt * 16 + l15] = f2bf(v);
      }
#pragma unroll
    for (int ps = 0; ps < 2; ++ps) {
      int row = ps * 8 + prow;
      int4 t = *(const int4*)(Ew + row * 72 + pcol);
      *(int4*)(C + (gmB + mt * 16 + row) * (long)Nsz + gnB + pcol) = t;
    }
  }
}

// ---------------- flash attention v14: v11 + balanced bx remap (best: 48.0-48.7 us) ----------------
// Per-block code identical to proven v11. The j -> (bx, bh-group) remap makes
// every CU's bx-triple sum 22/23 (r=j>>5, t=j&15; bx = [t, (t+8)&15,
// t<8?15-2t:30-2t][r]; bh-group = 2r+((j>>4)&1), bijective). Measured: -1%
// vs v11 — the balance was already near mean; the remaining 1570 cy/iter is
// the latency chain (barrier + LDS round-trips), not imbalance. Local floor.
__global__ __launch_bounds__(512) void attn_v14(const unsigned short* __restrict__ qkv,
                                                const unsigned short* __restrict__ vt,
                                                unsigned short* __restrict__ out) {
  const int blk = blockIdx.x;           // 0..767
  const int bh_lo = blk & 7;
  const int j = blk >> 3;               // 0..95
  const int r = j >> 5;                 // 0..2  (CU gets one j from each r)
  const int t = j & 15;
  int bx;
  if (r == 0)      bx = t;
  else if (r == 1) bx = (t + 8) & 15;
  else             bx = (t < 8) ? (15 - 2 * t) : (30 - 2 * t);
  const int bhHi6 = 2 * r + ((j >> 4) & 1);   // 0..5
  const int bh = bhHi6 * 8 + bh_lo;     // 0..47
  const int b = bh / NHEAD, h = bh % NHEAD;
  const int tid = threadIdx.x;
  const int w = tid >> 6;               // 0..7
  const int wl = w & 3;                 // wave within group
  const int g = w >> 2;                 // 0 = group A (heavy), 1 = group B
  const int lane = tid & 63, l15 = lane & 15, quad = lane >> 4;

  const int qtA = 31 - bx;              // heavy tile
  const int qtB = bx;                   // light tile
  const int qt = g ? qtB : qtA;         // this wave-group's tile
  const int niter = qtA + 1;
  const int nact = qt + 1;              // iterations this group computes

  __shared__ __align__(16) unsigned short Ks[2][64 * 64];   // [key][d], gran ^ key&7
  __shared__ __align__(16) unsigned short Vs[2][64 * 64];   // [d][key], gran ^ d&7
  __shared__ __align__(16) unsigned short Ps[8][16 * 64];   // per-wave [q][key]

  const long rowbase = (long)b * SEQ;
  unsigned short* Pw = &Ps[w][0];
  const unsigned short* vbh = vt + (long)bh * 64 * SEQ;
  const float LOG2E = 1.4426950408889634f;

  // staging: 512 threads cover one 64x64 K tile + one 64x64 V tile (16B each)
  const int krow = tid >> 3;                         // 0..63
  const int kgo = (((tid & 7) ^ (krow & 7)) * 8);    // swizzled granule offset
  const unsigned short* kbase = qkv + rowbase * 2304L + 768 + h * 64;
  const unsigned short* kp = kbase + (long)krow * 2304 + kgo;
  const unsigned short* vp = vbh + (long)krow * SEQ + kgo;

  // ---- Q for this group's tile (folded * LOG2E) ----
  const int qrow = qt * 64 + wl * 16 + l15;
  const int qg = qrow;
  bf16x8 qf[2];
#pragma unroll
  for (int s2 = 0; s2 < 2; ++s2) {
    int4 raw = *(const int4*)(qkv + (rowbase + qrow) * 2304L + h * 64 + s2 * 32 + quad * 8);
    const unsigned short* rp = (const unsigned short*)&raw;
#pragma unroll
    for (int j2 = 0; j2 < 8; ++j2)
      qf[s2][j2] = (__bf16)(bf2f(rp[j2]) * LOG2E);
  }

  float l_sum = 0.f;
  f32x4 o_acc[4] = {};

  // prologue: stage tile 0 into buf 0 (one K + one V load per thread)
  __builtin_amdgcn_global_load_lds(AS1C(kp), AS3(&Ks[0][0] + w * 512), 16, 0, 0);
  __builtin_amdgcn_global_load_lds(AS1C(vp), AS3(&Vs[0][0] + w * 512), 16, 0, 0);
  kp += 64 * 2304;
  vp += 64;

  for (int it = 0; it < niter; ++it) {
    __syncthreads();   // publish buf[it&1]; prefetched loads had a full iter to land
    if (it + 1 < niter) {
      const int nb = (it + 1) & 1;
      __builtin_amdgcn_global_load_lds(AS1C(kp), AS3(&Ks[nb][0] + w * 512), 16, 0, 0);
      __builtin_amdgcn_global_load_lds(AS1C(vp), AS3(&Vs[nb][0] + w * 512), 16, 0, 0);
      kp += 64 * 2304;
      vp += 64;
    }
    if (it >= nact) continue;   // group B done computing; stage + barrier only
    const unsigned short* Kc = &Ks[it & 1][0];
    const unsigned short* Vc = &Vs[it & 1][0];

    // ---- S^T = K Q^T : st[nt] rows = keys nt*16+quad*4+r, col q = l15 ----
    f32x4 st[4] = {};
    __builtin_amdgcn_s_setprio(1);
#pragma unroll
    for (int nt = 0; nt < 4; ++nt) {
      int key = nt * 16 + l15;
#pragma unroll
      for (int s2 = 0; s2 < 2; ++s2) {
        int phys = (s2 * 4 + quad) ^ (key & 7);
        bf16x8 kf = *(const bf16x8*)(Kc + key * 64 + phys * 8);
        st[nt] = __builtin_amdgcn_mfma_f32_16x16x32_bf16(kf, qf[s2], st[nt], 0, 0, 0);
      }
    }
    __builtin_amdgcn_s_setprio(0);

    // ---- causal mask: only this group's diagonal tile (it == qt) ----
    if (it == qt) {
#pragma unroll
      for (int nt = 0; nt < 4; ++nt) {
        int kg = it * 64 + nt * 16 + quad * 4;
#pragma unroll
        for (int rr = 0; rr < 4; ++rr)
          if (kg + rr > qg) st[nt][rr] = MASK_NEG;
      }
    }

    // ---- fixed-max softmax: p = 2^s ; per-lane partial, tree-reduced ----
    float sn[4];
#pragma unroll
    for (int nt = 0; nt < 4; ++nt) {
      float p0 = __builtin_amdgcn_exp2f(st[nt][0]);
      float p1 = __builtin_amdgcn_exp2f(st[nt][1]);
      float p2 = __builtin_amdgcn_exp2f(st[nt][2]);
      float p3 = __builtin_amdgcn_exp2f(st[nt][3]);
      st[nt][0] = p0; st[nt][1] = p1; st[nt][2] = p2; st[nt][3] = p3;
      sn[nt] = (p0 + p1) + (p2 + p3);
    }
    l_sum += (sn[0] + sn[1]) + (sn[2] + sn[3]);   // cross-quad reduce deferred

    // ---- P: cvt_pk pack 4 keys -> b64 store (granule ^ l15&7) ----
#pragma unroll
    for (int nt = 0; nt < 4; ++nt) {
      unsigned int lo, hi;
      asm("v_cvt_pk_bf16_f32 %0, %1, %2" : "=v"(lo) : "v"(st[nt][0]), "v"(st[nt][1]));
      asm("v_cvt_pk_bf16_f32 %0, %1, %2" : "=v"(hi) : "v"(st[nt][2]), "v"(st[nt][3]));
      int g8 = (nt * 2 + (quad >> 1)) ^ (l15 & 7);
      uint2 pv; pv.x = lo; pv.y = hi;
      *(uint2*)(Pw + l15 * 64 + g8 * 8 + (quad & 1) * 4) = pv;
    }

    // ---- O += P V  (same-wave LDS dependency, no barrier) ----
    __builtin_amdgcn_s_setprio(1);
#pragma unroll
    for (int c = 0; c < 2; ++c) {
      int phys = ((c * 4 + quad) ^ (l15 & 7)) * 8;
      bf16x8 pf = *(const bf16x8*)(Pw + l15 * 64 + phys);
#pragma unroll
      for (int ntd = 0; ntd < 4; ++ntd) {
        int d = ntd * 16 + l15;
        bf16x8 vf = *(const bf16x8*)(Vc + d * 64 + phys);
        o_acc[ntd] = __builtin_amdgcn_mfma_f32_16x16x32_bf16(pf, vf, o_acc[ntd], 0, 0, 0);
      }
    }
    __builtin_amdgcn_s_setprio(0);
  }

  // ---- epilogue: complete l_sum reduce, then O row q = quad*4+r ----
  l_sum += __shfl_xor(l_sum, 16);
  l_sum += __shfl_xor(l_sum, 32);
#pragma unroll
  for (int rr = 0; rr < 4; ++rr) {
    float lq = __shfl(l_sum, quad * 4 + rr);
    float inv = 1.f / lq;
    int q = qt * 64 + wl * 16 + quad * 4 + rr;
#pragma unroll
    for (int ntd = 0; ntd < 4; ++ntd) {
      int d = ntd * 16 + l15;
      out[(rowbase + q) * (long)NX + h * 64 + d] = f2bf(o_acc[ntd][rr] * inv);
    }
  }
}

// ---------------- fused residual add + (buggy additive) layernorm, vectorized ----------------
// 192 threads (3 waves), each owns 4 CONSECUTIVE elems: bf16 IO via ushort4
// (8 B/lane, coalescing sweet spot) instead of scalar 2 B loads (G13: scalar
// bf16 ~2-2.5x slower). fp32 IO via float4.
__global__ __launch_bounds__(192) void add_ln(const float* __restrict__ x_f,
                                              const unsigned short* __restrict__ x_b,
                                              const unsigned short* __restrict__ y_b,
                                              const float* __restrict__ g,
                                              const float* __restrict__ beta,
                                              float* __restrict__ out_f,
                                              unsigned short* __restrict__ out_b) {
  const int row = blockIdx.x, t = threadIdx.x;   // t = 0..191, NX = 192*4
  const long base = (long)row * NX;
  const int i0 = t * 4;
  float v[4];
  ushort4 yv = *(const ushort4*)(y_b + base + i0);
  if (x_f) {
    float4 xv = *(const float4*)(x_f + base + i0);
    v[0] = xv.x + bf2f(yv.x); v[1] = xv.y + bf2f(yv.y);
    v[2] = xv.z + bf2f(yv.z); v[3] = xv.w + bf2f(yv.w);
  } else {
    ushort4 xv = *(const ushort4*)(x_b + base + i0);
    v[0] = bf2f(xv.x) + bf2f(yv.x); v[1] = bf2f(xv.y) + bf2f(yv.y);
    v[2] = bf2f(xv.z) + bf2f(yv.z); v[3] = bf2f(xv.w) + bf2f(yv.w);
  }
  __shared__ float red[3];
  int wv = t >> 6, ln = t & 63;

  float ssum = (v[0] + v[1]) + (v[2] + v[3]);
#pragma unroll
  for (int sh = 32; sh >= 1; sh >>= 1) ssum += __shfl_xor(ssum, sh);
  if (ln == 0) red[wv] = ssum;
  __syncthreads();
  float u = (red[0] + red[1] + red[2]) * (1.f / NX);
  __syncthreads();

  float d0 = v[0] - u, d1 = v[1] - u, d2 = v[2] - u, d3 = v[3] - u;
  float sq = (d0 * d0 + d1 * d1) + (d2 * d2 + d3 * d3);
#pragma unroll
  for (int sh = 32; sh >= 1; sh >>= 1) sq += __shfl_xor(sq, sh);
  if (ln == 0) red[wv] = sq;
  __syncthreads();
  float s = (red[0] + red[1] + red[2]) * (1.f / NX);
  float rinv = rsqrtf(s + LN_EPS);

  float4 gv = *(const float4*)(g + i0);
  float4 bv = *(const float4*)(beta + i0);
  float o0 = gv.x + d0 * rinv + bv.x;
  float o1 = gv.y + d1 * rinv + bv.y;
  float o2 = gv.z + d2 * rinv + bv.z;
  float o3 = gv.w + d3 * rinv + bv.w;
  if (out_f) {
    float4 ov; ov.x = o0; ov.y = o1; ov.z = o2; ov.w = o3;
    *(float4*)(out_f + base + i0) = ov;
  } else {
    ushort4 ov;
    ov.x = f2bf(o0); ov.y = f2bf(o1); ov.z = f2bf(o2); ov.w = f2bf(o3);
    *(ushort4*)(out_b + base + i0) = ov;
  }
}

extern "C" void kernel_launch(void* const* d_in, const int* in_sizes, int n_in,
                              void* d_out, int out_size, void* d_ws, size_t ws_size,
                              hipStream_t stream) {
  const float* x      = (const float*)d_in[0];
  const float* w_attn = (const float*)d_in[1];
  const float* b_attn = (const float*)d_in[2];
  const float* w_proj = (const float*)d_in[3];
  const float* b_proj = (const float*)d_in[4];
  const float* ln1_g  = (const float*)d_in[5];
  const float* ln1_b  = (const float*)d_in[6];
  const float* w_fc   = (const float*)d_in[7];
  const float* b_fc   = (const float*)d_in[8];
  const float* w_fc2  = (const float*)d_in[9];
  const float* b_fc2  = (const float*)d_in[10];
  const float* ln2_g  = (const float*)d_in[11];
  const float* ln2_b  = (const float*)d_in[12];
  float* out = (float*)d_out;

  char* ws = (char*)d_ws;
  size_t off = 0;
  auto alloc = [&](size_t bytes) {
    char* p = ws + off;
    off += (bytes + 255) & ~(size_t)255;
    return p;
  };
  unsigned short* xb      = (unsigned short*)alloc((size_t)MROWS * NX * 2);
  unsigned short* wt_attn = (unsigned short*)alloc((size_t)2304 * 768 * 2);
  unsigned short* wt_proj = (unsigned short*)alloc((size_t)768 * 768 * 2);
  unsigned short* wt_fc   = (unsigned short*)alloc((size_t)3072 * 768 * 2);
  unsigned short* wt_fc2  = (unsigned short*)alloc((size_t)768 * 3072 * 2);
  unsigned short* qkv     = (unsigned short*)alloc((size_t)MROWS * 3072 * 2);
  unsigned short* hbuf    = qkv;        // fc output reuses qkv (dead after attn)
  unsigned short* abuf    = (unsigned short*)alloc((size_t)MROWS * NX * 2);
  unsigned short* mbuf    = abuf;       // fc2 output reuses abuf (dead after proj)
  unsigned short* nbuf    = (unsigned short*)alloc((size_t)MROWS * NX * 2);
  unsigned short* vtb     = nbuf;       // Vt[bh][d][s] lives in nbuf (dead until add_ln1)
  unsigned short* pout    = xb;         // proj output reuses xb (dead after qkv gemm)

  convert_f32_bf16<<<(MROWS * NX / 4 + 255) / 256, 256, 0, stream>>>(x, xb, MROWS * NX / 4);
  transpose_w<<<dim3(2304 / 32, 768 / 32), dim3(32, 8), 0, stream>>>(w_attn, wt_attn, 768, 2304);
  transpose_w<<<dim3(768 / 32, 768 / 32), dim3(32, 8), 0, stream>>>(w_proj, wt_proj, 768, 768);
  transpose_w<<<dim3(3072 / 32, 768 / 32), dim3(32, 8), 0, stream>>>(w_fc, wt_fc, 768, 3072);
  transpose_w<<<dim3(768 / 32, 3072 / 32), dim3(32, 8), 0, stream>>>(w_fc2, wt_fc2, 3072, 768);

  // qkv = xb @ w_attn^T + b_attn   (BN=128: 1152 blocks @ 2/CU, proven -7us)
  gemm_bt<0, 128><<<dim3(MROWS / 128, 2304 / 128), 256, 0, stream>>>(xb, wt_attn, b_attn, qkv, 2304, 768);
  // Vt[bh][d][s]
  transpose_v<<<dim3(SEQ / 64, 48), dim3(16, 16), 0, stream>>>(qkv, vtb);
  // a = causal_attention(qkv)  (768 pair-blocks, balanced bx remap)
  attn_v14<<<768, 512, 0, stream>>>(qkv, vtb, abuf);
  // pout = a @ w_proj^T + b_proj   (BN=64: 768 blocks = exactly 3/CU — R10
  // counters showed BN=128's 1.5/CU = 12% occupancy regressed fc2; same shape)
  gemm_bt<0, 64><<<dim3(MROWS / 128, 768 / 64), 256, 0, stream>>>(abuf, wt_proj, b_proj, pout, 768, 768);
  // n = ln1(x + pout)   (overwrites nbuf == vtb, Vt is dead now)
  add_ln<<<MROWS, 192, 0, stream>>>(x, nullptr, pout, ln1_g, ln1_b, nullptr, nbuf);
  // h = relu(n @ w_fc^T + b_fc)   (1536 blocks = exactly 3 rounds @ 2/CU)
  gemm_bt<1, 128><<<dim3(MROWS / 128, 3072 / 128), 256, 0, stream>>>(nbuf, wt_fc, b_fc, hbuf, 3072, 768);
  // m = h @ w_fc2^T + b_fc2   (BN=64: 768 blocks = 3/CU; at BN=128 measured
  // 49.4us @ 12% occupancy — reverted)
  gemm_bt<0, 64><<<dim3(MROWS / 128, 768 / 64), 256, 0, stream>>>(hbuf, wt_fc2, b_fc2, mbuf, 768, 3072);
  // out = ln2(n + m)  (fp32 to d_out)
  add_ln<<<MROWS, 192, 0, stream>>>(nullptr, nbuf, mbuf, ln2_g, ln2_b, out, nullptr);
}